// Round 11
// baseline (45.198 us; speedup 1.0000x reference)
//
#include <hip/hip_runtime.h>
#include <math.h>

#define MA 64
#define ME 256
#define DM 256
#define DQK 32
#define ENVSTRIDE (MA * ME)            // 16384 floats per env
#define MASKVAL -998244352.0f          // bf16-rounded -1e9 (matches reference)
#define QK_SCALE 0.17677669529663687f  // 1/sqrt(32)
#define KSTR 40                        // LDS row stride in ushorts (80B)
#define ESTR16 32768                   // staging env stride in u16 (=64KB, the env logits slot)

typedef __attribute__((ext_vector_type(8))) short bf16x8;
typedef __attribute__((ext_vector_type(4))) float f32x4;
typedef unsigned short u16;

__device__ __forceinline__ int lb(const int* __restrict__ a, int n, int v){
  int lo = 0, hi = n;
  while (lo < hi){ int mid = (lo + hi) >> 1; if (a[mid] < v) lo = mid + 1; else hi = mid; }
  return lo;
}
// round-to-nearest-even f32 -> bf16 (validated rounds 8-10)
__device__ __forceinline__ unsigned pk2bf(float lo, float hi){
  unsigned ul = __float_as_uint(lo); ul = ul + 0x7FFFu + ((ul >> 16) & 1u);
  unsigned uh = __float_as_uint(hi); uh = uh + 0x7FFFu + ((uh >> 16) & 1u);
  return (ul >> 16) | (uh & 0xFFFF0000u);
}
__device__ __forceinline__ u16 f2bu(float f){
  unsigned u = __float_as_uint(f);
  return (u16)((u + 0x7FFFu + ((u >> 16) & 1u)) >> 16);
}

// ===== K0: pack Wk|Wq into bf16 MFMA-fragment order (validated layout, round 10) =====
__global__ __launch_bounds__(256)
void pack_w(const float* __restrict__ Wk, const float* __restrict__ Wq,
            unsigned* __restrict__ wfr_g){
  const int t = threadIdx.x;
  #pragma unroll
  for (int ii = 0; ii < 32; ++ii) {
    const int i = t + ii * 256;
    const int p = i & 3, ln = (i >> 2) & 63, nt = (i >> 8) & 1, kk = (i >> 9) & 7, wh = i >> 12;
    const int k0  = kk * 32 + (ln >> 4) * 8 + 2 * p;
    const int col = nt * 16 + (ln & 15);
    const float* W = wh ? Wq : Wk;
    wfr_g[i] = pk2bf(W[(size_t)k0 * DQK + col], W[(size_t)(k0 + 1) * DQK + col]);
  }
}

// ===== K1: projection over GLOBAL 16-row tiles (uniform cost -> perfect balance) =====
__global__ __launch_bounds__(256)
void proj_mfma(const float* __restrict__ x,
               const float* __restrict__ bq, const float* __restrict__ bk,
               const int* __restrict__ actors, const int* __restrict__ qindices,
               const int* __restrict__ actees, const int* __restrict__ kindices,
               int A, int E, int nKt, int nTot,
               const unsigned* __restrict__ wfr_g, u16* __restrict__ stage)
{
  const int lane = threadIdx.x & 63, w = threadIdx.x >> 6;
  const int wid = blockIdx.x * 4 + w;
  if (wid >= nTot) return;

  const bool isk  = (wid < nKt);
  const int  tile = isk ? wid : wid - nKt;
  const int  n    = isk ? E : A;
  const int  rbase = tile << 4;
  const int  lr = lane & 15, lq = lane >> 4;

  const int arow = min(rbase + lr, n - 1);
  const int src  = isk ? actees[arow] : actors[arow];
  const float* xr = x + (size_t)src * DM + lq * 8;

  // B-fragments: 16 coalesced 16B loads, L1/L2-hot (32KB total shared by all waves)
  const unsigned* fb = wfr_g + (isk ? 0 : 4096) + lane * 4;
  bf16x8 bfr[8][2];
  #pragma unroll
  for (int kk = 0; kk < 8; ++kk) {
    bfr[kk][0] = *(const bf16x8*)(fb + kk * 512);
    bfr[kk][1] = *(const bf16x8*)(fb + kk * 512 + 256);
  }
  const float* bb = isk ? bk : bq;
  const float bv0 = bb[lr], bv1 = bb[16 + lr];

  float4 cx[16];
  #pragma unroll
  for (int kk = 0; kk < 8; ++kk) {
    cx[2*kk]   = *(const float4*)(xr + kk * 32);
    cx[2*kk+1] = *(const float4*)(xr + kk * 32 + 4);
  }

  f32x4 a0 = {bv0, bv0, bv0, bv0}, a1 = {bv1, bv1, bv1, bv1};
  #pragma unroll
  for (int kk = 0; kk < 8; ++kk) {
    union { unsigned u[4]; bf16x8 v; } fa;
    fa.u[0] = pk2bf(cx[2*kk].x,   cx[2*kk].y);
    fa.u[1] = pk2bf(cx[2*kk].z,   cx[2*kk].w);
    fa.u[2] = pk2bf(cx[2*kk+1].x, cx[2*kk+1].y);
    fa.u[3] = pk2bf(cx[2*kk+1].z, cx[2*kk+1].w);
    a0 = __builtin_amdgcn_mfma_f32_16x16x32_bf16(fa.v, bfr[kk][0], a0, 0, 0, 0);
    a1 = __builtin_amdgcn_mfma_f32_16x16x32_bf16(fa.v, bfr[kk][1], a1, 0, 0, 0);
  }

  // D: col = lane&15, row = 4*(lane>>4)+reg (validated). Scatter bf16 to env staging.
  #pragma unroll
  for (int reg = 0; reg < 4; ++reg) {
    const int row = rbase + 4 * lq + reg;
    if (row < n) {
      const int idx = isk ? kindices[row] : qindices[row];
      const int env = isk ? (idx >> 8) : (idx >> 6);
      const int pos = isk ? (idx & (ME - 1)) : (idx & (MA - 1));
      u16* dst = stage + (size_t)env * ESTR16 + (isk ? 0 : 8192) + pos * 32;
      dst[lr]      = f2bu(a0[reg]);
      dst[16 + lr] = f2bu(a1[reg]);
    }
  }
}

// ===== K2: logits + softmax per env (round-9 datapath; kb/qsm from staging copy) =====
__global__ __launch_bounds__(256)
void logits_kernel(const int* __restrict__ qindices, const int* __restrict__ kindices,
                   const int* __restrict__ prev_actions, const u16* __restrict__ stage,
                   int A, int E, float* __restrict__ out)
{
  __shared__ u16 kb[ME * KSTR];    // 20 KB
  __shared__ u16 qsm[MA * KSTR];   //  5 KB
  __shared__ int srange[4];

  const int t = threadIdx.x, b = blockIdx.x;
  if (t < 4) {
    const int* arr = (t < 2) ? qindices : kindices;
    const int nn = (t < 2) ? A : E;
    const int vv = (t == 0) ? b * MA : (t == 1) ? (b + 1) * MA
                 : (t == 2) ? b * ME : (b + 1) * ME;
    srange[t] = lb(arr, nn, vv);
  }

  // copy staged bf16 K/Q -> LDS (coalesced b128; garbage rows are finite & masked later)
  const u16* sk = stage + (size_t)b * ESTR16;
  const u16* sq = sk + 8192;
  #pragma unroll
  for (int ii = 0; ii < 4; ++ii) {
    const int i = t * 4 + ii;                 // 1024 frags of 8 u16
    const int row = i >> 2, c8 = (i & 3) * 8;
    *(bf16x8*)&kb[row * KSTR + c8] = *(const bf16x8*)(sk + i * 8);
  }
  {
    const int row = t >> 2, c8 = (t & 3) * 8;
    *(bf16x8*)&qsm[row * KSTR + c8] = *(const bf16x8*)(sq + t * 8);
  }
  __syncthreads();

  const int qstart = srange[0], qlen = srange[1] - srange[0];
  const int klen   = srange[3] - srange[2];

  const int lane = t & 63, w = t >> 6;
  const int lr = lane & 15, lq = lane >> 4;

  float* out_lg = out + (size_t)3 * A + (size_t)b * ENVSTRIDE;
  const int row0 = 16 * w;

  if (row0 >= qlen) {          // fully padded rows: MASKVAL fill
    const float4 mv = make_float4(MASKVAL, MASKVAL, MASKVAL, MASKVAL);
    float4* o4 = (float4*)out_lg;
    #pragma unroll
    for (int rr = 0; rr < 16; ++rr) o4[(row0 + rr) * 64 + lane] = mv;
    return;
  }

  const bf16x8 afr = *(const bf16x8*)&qsm[(row0 + lr) * KSTR + lq * 8];
  f32x4 acc[16];
  #pragma unroll
  for (int nt = 0; nt < 16; ++nt) {
    const bf16x8 bfr2 = *(const bf16x8*)&kb[(16 * nt + lr) * KSTR + lq * 8];
    f32x4 z = {0.f, 0.f, 0.f, 0.f};
    acc[nt] = __builtin_amdgcn_mfma_f32_16x16x32_bf16(afr, bfr2, z, 0, 0, 0);
  }

  int par[4];
  float m[4], spa[4], es[4], ts[4];
  #pragma unroll
  for (int reg = 0; reg < 4; ++reg) {
    const int r = row0 + 4 * lq + reg;
    par[reg] = (r < qlen) ? (prev_actions[qstart + r] & (ME - 1)) : -1;
    m[reg] = MASKVAL; spa[reg] = MASKVAL; es[reg] = 0.f; ts[reg] = 0.f;
  }

  #pragma unroll
  for (int nt = 0; nt < 16; ++nt) {
    const int col = 16 * nt + lr;
    const bool kv = (col < klen);
    #pragma unroll
    for (int reg = 0; reg < 4; ++reg) {
      const float d = kv ? acc[nt][reg] * QK_SCALE : MASKVAL;
      acc[nt][reg] = d;
      m[reg] = fmaxf(m[reg], d);
      if (col == par[reg]) spa[reg] = d;
    }
  }
  #pragma unroll
  for (int off = 1; off < 16; off <<= 1) {
    #pragma unroll
    for (int reg = 0; reg < 4; ++reg) {
      m[reg]   = fmaxf(m[reg],   __shfl_xor(m[reg],   off));
      spa[reg] = fmaxf(spa[reg], __shfl_xor(spa[reg], off));
    }
  }
  #pragma unroll
  for (int nt = 0; nt < 16; ++nt) {
    #pragma unroll
    for (int reg = 0; reg < 4; ++reg) {
      const float dd = acc[nt][reg] - m[reg];
      if (dd > -80.f) { const float e = __expf(dd); es[reg] += e; ts[reg] += e * dd; }
    }
  }
  #pragma unroll
  for (int off = 1; off < 16; off <<= 1) {
    #pragma unroll
    for (int reg = 0; reg < 4; ++reg) {
      es[reg] += __shfl_xor(es[reg], off);
      ts[reg] += __shfl_xor(ts[reg], off);
    }
  }

  #pragma unroll
  for (int nt = 0; nt < 16; ++nt) {
    #pragma unroll
    for (int reg = 0; reg < 4; ++reg) {
      const int r = row0 + 4 * lq + reg;
      out_lg[r * ME + 16 * nt + lr] = (r < qlen) ? acc[nt][reg] : MASKVAL;
    }
  }
  if (lr == 0) {
    #pragma unroll
    for (int reg = 0; reg < 4; ++reg) {
      const int r = row0 + 4 * lq + reg;
      if (r < qlen) {
        const float lS = __logf(fmaxf(es[reg], 1e-30f));
        out[qstart + r]         = (float)par[reg];
        out[A + qstart + r]     = spa[reg] - m[reg] - lS;
        out[2 * A + qstart + r] = lS - ts[reg] / es[reg];
      }
    }
  }
}

extern "C" void kernel_launch(void* const* d_in, const int* in_sizes, int n_in,
                              void* d_out, int out_size, void* d_ws, size_t ws_size,
                              hipStream_t stream) {
  const float* x  = (const float*)d_in[0];
  const float* Wq = (const float*)d_in[1];
  const float* bq = (const float*)d_in[2];
  const float* Wk = (const float*)d_in[3];
  const float* bk = (const float*)d_in[4];
  const int* actors       = (const int*)d_in[5];
  const int* qindices     = (const int*)d_in[6];
  const int* actees       = (const int*)d_in[7];
  const int* kindices     = (const int*)d_in[8];
  const int* prev_actions = (const int*)d_in[9];

  const int A = in_sizes[5];
  const int E = in_sizes[7];
  const int B = (out_size - 3 * A) / ENVSTRIDE;
  if (B <= 0) return;

  float* out = (float*)d_out;
  // staging lives inside the logits region: env b uses the front 20KB of its 64KB slot;
  // W fragments live in the back half (32KB) of env 0's slot (read before logits overwrite)
  u16* stage = (u16*)(out + (((size_t)3 * A + 3) & ~(size_t)3));
  unsigned* wfr_g = (unsigned*)(stage + 16384);   // byte offset 32768 in env 0's slot

  const int nKt = (E + 15) / 16;
  const int nQt = (A + 15) / 16;
  const int nTot = nKt + nQt;

  pack_w<<<dim3(1), dim3(256), 0, stream>>>(Wk, Wq, wfr_g);
  proj_mfma<<<dim3((nTot + 3) / 4), dim3(256), 0, stream>>>(
      x, bq, bk, actors, qindices, actees, kindices, A, E, nKt, nTot, wfr_g, stage);
  logits_kernel<<<dim3(B), dim3(256), 0, stream>>>(
      qindices, kindices, prev_actions, stage, A, E, out);
}

// Round 12
// 44.462 us; speedup vs baseline: 1.0166x; 1.0166x over previous
//
#include <hip/hip_runtime.h>
#include <math.h>

#define MA 64
#define ME 256
#define DM 256
#define DQK 32
#define ENVSTRIDE (MA * ME)            // 16384 floats per env
#define MASKVAL -998244352.0f          // bf16-rounded -1e9 (matches reference)
#define QK_SCALE 0.17677669529663687f  // 1/sqrt(32)
#define KSTR 40                        // LDS row stride in ushorts (80B)

typedef __attribute__((ext_vector_type(8))) short bf16x8;
typedef __attribute__((ext_vector_type(4))) float f32x4;
typedef unsigned short u16;

__device__ __forceinline__ int lb(const int* __restrict__ a, int n, int v){
  int lo = 0, hi = n;
  while (lo < hi){ int mid = (lo + hi) >> 1; if (a[mid] < v) lo = mid + 1; else hi = mid; }
  return lo;
}
// round-to-nearest-even f32 -> bf16 (validated rounds 8-11)
__device__ __forceinline__ unsigned pk2bf(float lo, float hi){
  unsigned ul = __float_as_uint(lo); ul = ul + 0x7FFFu + ((ul >> 16) & 1u);
  unsigned uh = __float_as_uint(hi); uh = uh + 0x7FFFu + ((uh >> 16) & 1u);
  return (ul >> 16) | (uh & 0xFFFF0000u);
}
__device__ __forceinline__ u16 f2bu(float f){
  unsigned u = __float_as_uint(f);
  return (u16)((u + 0x7FFFu + ((u >> 16) & 1u)) >> 16);
}

// ===== K0: pack Wk|Wq into bf16 MFMA-fragment order into d_ws (layout validated r11) =====
__global__ __launch_bounds__(256)
void pack_w(const float* __restrict__ Wk, const float* __restrict__ Wq,
            unsigned* __restrict__ wfr_g){
  const int t = threadIdx.x;
  #pragma unroll
  for (int ii = 0; ii < 32; ++ii) {
    const int i = t + ii * 256;
    const int p = i & 3, ln = (i >> 2) & 63, nt = (i >> 8) & 1, kk = (i >> 9) & 7, wh = i >> 12;
    const int k0  = kk * 32 + (ln >> 4) * 8 + 2 * p;
    const int col = nt * 16 + (ln & 15);
    const float* W = wh ? Wq : Wk;
    wfr_g[i] = pk2bf(W[(size_t)k0 * DQK + col], W[(size_t)(k0 + 1) * DQK + col]);
  }
}

// ===== K1: fused per-env kernel, 512 threads (8 waves) =====
__global__ __launch_bounds__(512, 4)
void fused_env(const float* __restrict__ x,
               const float* __restrict__ bq, const float* __restrict__ bk,
               const int* __restrict__ actors, const int* __restrict__ qindices,
               const int* __restrict__ actees, const int* __restrict__ kindices,
               const int* __restrict__ prev_actions,
               const unsigned* __restrict__ wfr_g,
               int A, int E, float* __restrict__ out)
{
  __shared__ u16 kb[ME * KSTR];      // 20 KB bf16 keys
  __shared__ u16 qsm[MA * KSTR];     //  5 KB bf16 queries
  __shared__ float red[8][16][4];    //  2 KB softmax partials (m, spa, es, ts)
  __shared__ int srange[4];

  const int t = threadIdx.x, b = blockIdx.x;
  const int lane = t & 63, w = t >> 6;
  const int lr = lane & 15, lq = lane >> 4;

  if (t < 4) {
    const int* arr = (t < 2) ? qindices : kindices;
    const int nn = (t < 2) ? A : E;
    const int vv = (t == 0) ? b * MA : (t == 1) ? (b + 1) * MA
                 : (t == 2) ? b * ME : (b + 1) * ME;
    srange[t] = lb(arr, nn, vv);
  }
  __syncthreads();
  const int qstart = srange[0], qlen = srange[1] - srange[0];
  const int kstart = srange[2], klen = srange[3] - srange[2];

  // ---- projection: merged K+Q tile list, 8-wave strided (datapath validated r9-r11) ----
  const int kt = (klen + 15) >> 4;
  const int qt = (qlen + 15) >> 4;
  const int ntiles = kt + qt;

  for (int i = w; i < ntiles; i += 8) {
    const bool isk = (i < kt);
    const int  rbase = isk ? (i << 4) : ((i - kt) << 4);
    const int  len   = isk ? klen : qlen;
    const int  start = isk ? kstart : qstart;
    const int* gath  = isk ? actees : actors;
    u16*       dst   = isk ? kb : qsm;
    const unsigned* fb = wfr_g + (isk ? 0 : 4096) + lane * 4;

    const int arow = start + min(rbase + lr, len - 1);
    const float* xr = x + (size_t)gath[arow] * DM + lq * 8;

    const float* bb = isk ? bk : bq;
    const float bv0 = bb[lr], bv1 = bb[16 + lr];
    f32x4 a0 = {bv0, bv0, bv0, bv0}, a1 = {bv1, bv1, bv1, bv1};

    #pragma unroll
    for (int h = 0; h < 2; ++h) {               // two half-tiles keep VGPR <= 128
      float4 cx[8];
      #pragma unroll
      for (int k2 = 0; k2 < 4; ++k2) {
        cx[2*k2]   = *(const float4*)(xr + h * 128 + k2 * 32);
        cx[2*k2+1] = *(const float4*)(xr + h * 128 + k2 * 32 + 4);
      }
      #pragma unroll
      for (int k2 = 0; k2 < 4; ++k2) {
        const int kk = h * 4 + k2;
        union { unsigned u[4]; bf16x8 v; } fa;
        fa.u[0] = pk2bf(cx[2*k2].x,   cx[2*k2].y);
        fa.u[1] = pk2bf(cx[2*k2].z,   cx[2*k2].w);
        fa.u[2] = pk2bf(cx[2*k2+1].x, cx[2*k2+1].y);
        fa.u[3] = pk2bf(cx[2*k2+1].z, cx[2*k2+1].w);
        const bf16x8 b0 = *(const bf16x8*)(fb + kk * 512);
        const bf16x8 b1 = *(const bf16x8*)(fb + kk * 512 + 256);
        a0 = __builtin_amdgcn_mfma_f32_16x16x32_bf16(fa.v, b0, a0, 0, 0, 0);
        a1 = __builtin_amdgcn_mfma_f32_16x16x32_bf16(fa.v, b1, a1, 0, 0, 0);
      }
    }
    // D: col = lane&15, row = 4*(lane>>4)+reg (validated)
    #pragma unroll
    for (int reg = 0; reg < 4; ++reg) {
      const int row = rbase + 4 * lq + reg;
      if (row < len) {
        dst[row * KSTR + lr]      = f2bu(a0[reg]);
        dst[row * KSTR + 16 + lr] = f2bu(a1[reg]);
      }
    }
  }
  __syncthreads();

  // ---- logits: wave = (q-tile, column-half). 8 MFMAs per wave ----
  float* out_lg = out + (size_t)3 * A + (size_t)b * ENVSTRIDE;
  const int tt = w >> 1, ch = w & 1;
  const int row0 = 16 * tt;
  const bool live = (row0 < qlen);

  f32x4 acc[8];
  int par[4];
  float m[4], spa[4], es[4], ts[4];

  if (live) {
    const bf16x8 afr = *(const bf16x8*)&qsm[(row0 + lr) * KSTR + lq * 8];
    #pragma unroll
    for (int nt = 0; nt < 8; ++nt) {
      const int ntg = 8 * ch + nt;
      const bf16x8 bfr2 = *(const bf16x8*)&kb[(16 * ntg + lr) * KSTR + lq * 8];
      f32x4 z = {0.f, 0.f, 0.f, 0.f};
      acc[nt] = __builtin_amdgcn_mfma_f32_16x16x32_bf16(afr, bfr2, z, 0, 0, 0);
    }
    #pragma unroll
    for (int reg = 0; reg < 4; ++reg) {
      const int r = row0 + 4 * lq + reg;
      par[reg] = (r < qlen) ? (prev_actions[qstart + r] & (ME - 1)) : -1;
      m[reg] = MASKVAL; spa[reg] = MASKVAL; es[reg] = 0.f; ts[reg] = 0.f;
    }
    #pragma unroll
    for (int nt = 0; nt < 8; ++nt) {
      const int col = 128 * ch + 16 * nt + lr;
      const bool kv = (col < klen);
      #pragma unroll
      for (int reg = 0; reg < 4; ++reg) {
        const float d = kv ? acc[nt][reg] * QK_SCALE : MASKVAL;
        acc[nt][reg] = d;
        m[reg] = fmaxf(m[reg], d);
        if (col == par[reg]) spa[reg] = d;
      }
    }
    #pragma unroll
    for (int off = 1; off < 16; off <<= 1) {
      #pragma unroll
      for (int reg = 0; reg < 4; ++reg) {
        m[reg]   = fmaxf(m[reg],   __shfl_xor(m[reg],   off));
        spa[reg] = fmaxf(spa[reg], __shfl_xor(spa[reg], off));
      }
    }
    #pragma unroll
    for (int nt = 0; nt < 8; ++nt) {
      #pragma unroll
      for (int reg = 0; reg < 4; ++reg) {
        const float dd = acc[nt][reg] - m[reg];
        if (dd > -80.f) { const float e = __expf(dd); es[reg] += e; ts[reg] += e * dd; }
      }
    }
    #pragma unroll
    for (int off = 1; off < 16; off <<= 1) {
      #pragma unroll
      for (int reg = 0; reg < 4; ++reg) {
        es[reg] += __shfl_xor(es[reg], off);
        ts[reg] += __shfl_xor(ts[reg], off);
      }
    }
    if (lr == 0) {
      #pragma unroll
      for (int reg = 0; reg < 4; ++reg) {
        const int ridx = 4 * lq + reg;
        red[w][ridx][0] = m[reg];  red[w][ridx][1] = spa[reg];
        red[w][ridx][2] = es[reg]; red[w][ridx][3] = ts[reg];
      }
    }
  }
  __syncthreads();

  if (!live) {       // fully padded tile: MASKVAL fill of this wave's column half
    const float4 mv = make_float4(MASKVAL, MASKVAL, MASKVAL, MASKVAL);
    float4* o4 = (float4*)out_lg;
    #pragma unroll
    for (int rr = 0; rr < 8; ++rr) {
      const int r = row0 + 2 * rr + (lane >> 5);
      o4[r * 64 + 32 * ch + (lane & 31)] = mv;
    }
    return;
  }

  // merge with partner wave (other column half) — online-softmax merge (validated r4/r5)
  const int other = w ^ 1;
  #pragma unroll
  for (int reg = 0; reg < 4; ++reg) {
    const int ridx = 4 * lq + reg;
    const float mb  = red[other][ridx][0];
    const float spb = red[other][ridx][1];
    const float eb  = red[other][ridx][2];
    const float tb  = red[other][ridx][3];
    const float M  = fmaxf(m[reg], mb);
    const float sa = __expf(m[reg] - M), sb = __expf(mb - M);
    ts[reg]  = (ts[reg] + es[reg] * (m[reg] - M)) * sa + (tb + eb * (mb - M)) * sb;
    es[reg]  = es[reg] * sa + eb * sb;
    m[reg]   = M;
    spa[reg] = fmaxf(spa[reg], spb);
  }

  // write this wave's column half of the logits
  #pragma unroll
  for (int nt = 0; nt < 8; ++nt) {
    #pragma unroll
    for (int reg = 0; reg < 4; ++reg) {
      const int r = row0 + 4 * lq + reg;
      out_lg[r * ME + 128 * ch + 16 * nt + lr] = (r < qlen) ? acc[nt][reg] : MASKVAL;
    }
  }
  if (ch == 0 && lr == 0) {
    #pragma unroll
    for (int reg = 0; reg < 4; ++reg) {
      const int r = row0 + 4 * lq + reg;
      if (r < qlen) {
        const float lS = __logf(fmaxf(es[reg], 1e-30f));
        out[qstart + r]         = (float)par[reg];
        out[A + qstart + r]     = spa[reg] - m[reg] - lS;
        out[2 * A + qstart + r] = lS - ts[reg] / es[reg];
      }
    }
  }
}

extern "C" void kernel_launch(void* const* d_in, const int* in_sizes, int n_in,
                              void* d_out, int out_size, void* d_ws, size_t ws_size,
                              hipStream_t stream) {
  const float* x  = (const float*)d_in[0];
  const float* Wq = (const float*)d_in[1];
  const float* bq = (const float*)d_in[2];
  const float* Wk = (const float*)d_in[3];
  const float* bk = (const float*)d_in[4];
  const int* actors       = (const int*)d_in[5];
  const int* qindices     = (const int*)d_in[6];
  const int* actees       = (const int*)d_in[7];
  const int* kindices     = (const int*)d_in[8];
  const int* prev_actions = (const int*)d_in[9];

  const int A = in_sizes[5];
  const int E = in_sizes[7];
  const int B = (out_size - 3 * A) / ENVSTRIDE;
  if (B <= 0) return;

  unsigned* wfr_g = (unsigned*)d_ws;   // 32 KB of scratch for packed W fragments

  pack_w<<<dim3(1), dim3(256), 0, stream>>>(Wk, Wq, wfr_g);
  fused_env<<<dim3(B), dim3(512), 0, stream>>>(
      x, bq, bk, actors, qindices, actees, kindices, prev_actions,
      wfr_g, A, E, (float*)d_out);
}